// Round 9
// baseline (217.695 us; speedup 1.0000x reference)
//
#include <hip/hip_runtime.h>
#include <math.h>

#define Bb 8
#define Hh 8
#define LQ 2048
#define LK 2048
#define Dd 64
#define Uu 40
#define NCH 64
#define CHUNK (LK / NCH)   // 32
#define NSPL 8
#define CK (LK / NSPL)     // 256 keys per split-K chunk
#define UW 10              // queries per wave in k_attn_part

typedef float f32x4 __attribute__((ext_vector_type(4)));

__device__ __forceinline__ float dot4(float4 a, float4 b) {
    return a.x * b.x + a.y * b.y + a.z * b.z + a.w * b.w;
}

// ---------------- Stage 1: M[b,h,q] = max_s(QK_s) - mean_s(QK_s) ----------------
// (r8 version — measured at the per-CU vector-load transaction wall, ~84 µs)
__global__ __launch_bounds__(256) void k_sampleM(
    const float* __restrict__ Qp, const float* __restrict__ Kp,
    const int* __restrict__ idxs, float* __restrict__ M)
{
    int b  = blockIdx.x & 7;      // b-major: round-robin XCD dispatch pins K[b] per XCD L2
    int qt = blockIdx.x >> 3;     // 0..255 (8 queries per block)
    int t = threadIdx.x;
    int lane = t & 63, wave = t >> 6;

    __shared__ int sIdx[8 * Uu];
    for (int i = t; i < 8 * Uu; i += 256)
        sIdx[i] = idxs[(qt * 8) * Uu + i];
    __syncthreads();

    const size_t HD = 512;
    const float* Kb = Kp + (size_t)b * LK * HD + lane * 4;

#pragma unroll
    for (int i = 0; i < 2; ++i) {
        int lq = wave * 2 + i;
        int q  = qt * 8 + lq;
        const int* sI = &sIdx[lq * Uu];
#pragma unroll
        for (int ph = 0; ph < 2; ++ph) {
            f32x4 qa = __builtin_nontemporal_load(
                reinterpret_cast<const f32x4*>(
                    Qp + ((size_t)b * LQ + q) * HD + ph * 256) + lane);

            float mx = -INFINITY, sm = 0.f;
#pragma unroll 8
            for (int s = 0; s < Uu; ++s) {
                int kidx = sI[s];
                f32x4 kv = *reinterpret_cast<const f32x4*>(
                    Kb + (size_t)kidx * HD + ph * 256);
                float p = qa[0] * kv[0] + qa[1] * kv[1]
                        + qa[2] * kv[2] + qa[3] * kv[3];
                p += __shfl_xor(p, 1, 64);
                p += __shfl_xor(p, 2, 64);
                p += __shfl_xor(p, 4, 64);
                p += __shfl_xor(p, 8, 64);
                mx = fmaxf(mx, p); sm += p;
            }
            if ((lane & 15) == 0) {
                int h = ph * 4 + (lane >> 4);
                __builtin_nontemporal_store(
                    mx - sm * (1.0f / Uu), &M[((b * 8 + h) << 11) + q]);
            }
        }
    }
}

// ---------------- Stage 2: top-40 per (b,h) — single wave, shuffle argmax ----------------
__global__ __launch_bounds__(64) void k_topk(
    const float* __restrict__ M, int* __restrict__ Mtop, int* __restrict__ sel)
{
    int bh = blockIdx.x;
    int lane = threadIdx.x;
    __shared__ float Ml[LQ];

    for (int j = lane; j < LQ; j += 64) {
        Ml[j] = M[bh * LQ + j];
        sel[bh * LQ + j] = -1;
    }
    __syncthreads();

    float lv = -INFINITY; int li = LQ;
    for (int j = 0; j < 32; ++j) {
        int idx = lane + 64 * j;
        float x = Ml[idx];
        if (x > lv) { lv = x; li = idx; }
    }

    for (int u = 0; u < Uu; ++u) {
        float v = lv; int id = li;
#pragma unroll
        for (int off = 32; off > 0; off >>= 1) {
            float ov = __shfl_xor(v, off, 64);
            int   oi = __shfl_xor(id, off, 64);
            if (ov > v || (ov == v && oi < id)) { v = ov; id = oi; }
        }
        if (lane == 0) {
            Mtop[bh * Uu + u] = id;
            sel[bh * LQ + id] = u;
        }
        if ((id & 63) == lane) {        // owner invalidates + rescans its column
            Ml[id] = -INFINITY;
            lv = -INFINITY; li = LQ;
            for (int j = 0; j < 32; ++j) {
                int idx = lane + 64 * j;
                float x = Ml[idx];
                if (x > lv) { lv = x; li = idx; }
            }
        }
    }
}

// ---------------- Stage 3: split-K partial attention, LDS-staged K/V tiles ----------------
// Block = (bh, chunk). K tile [64][65] and transposed V tile sVt[d][kk] staged coalesced
// once per block (was: 4 waves x per-lane scattered loads). 65-pad => 2-way (free) LDS reads.
__global__ __launch_bounds__(256) void k_attn_part(
    const float* __restrict__ Qp, const float* __restrict__ Kp,
    const float* __restrict__ Vp, const int* __restrict__ Mtop,
    float* __restrict__ pacc, float* __restrict__ pl)
{
    int bh = blockIdx.x >> 3;
    int c  = blockIdx.x & (NSPL - 1);
    int b = bh >> 3, h = bh & 7;
    int t = threadIdx.x;
    int lane = t & 63, wave = t >> 6;

    __shared__ float sQ[Uu][Dd];
    __shared__ int   sP[Uu];
    __shared__ float sK[64][65];
    __shared__ float sVt[64][65];     // sVt[d][kk]
    __shared__ float sE[4][UW][Dd];

    if (t < Uu) sP[t] = Mtop[bh * Uu + t];
    __syncthreads();

    int pmax = 0;
    for (int u = 0; u < Uu; ++u) pmax = max(pmax, sP[u]);

    for (int i = t; i < Uu * Dd; i += 256) {
        int u = i >> 6, d = i & 63;
        sQ[u][d] = Qp[(((size_t)b * LQ + sP[u]) * Hh + h) * Dd + d];
    }
    __syncthreads();

    float acc[UW], lsum[UW];
#pragma unroll
    for (int i = 0; i < UW; ++i) { acc[i] = 0.f; lsum[i] = 0.f; }

    const int u0 = wave * UW;
    for (int tt = 0; tt < CK / 64; ++tt) {
        int k0 = c * CK + tt * 64;
        if (pmax < k0) break;             // block-uniform: tiles ascending

        // stage K tile (rows k0..k0+63, this head's 256B slice) — coalesced
        for (int i = t; i < 64 * 16; i += 256) {
            int r = i >> 4, j = i & 15;
            float4 kv = *reinterpret_cast<const float4*>(
                Kp + (((size_t)b * LK + k0 + r) * Hh + h) * Dd + j * 4);
            *reinterpret_cast<float4*>(&sK[r][j * 4]) = kv;
        }
        // stage V tile transposed — coalesced read, 2-way-free scatter write
        for (int i = t; i < 64 * 16; i += 256) {
            int r = i >> 4, j = i & 15;
            float4 vv = *reinterpret_cast<const float4*>(
                Vp + (((size_t)b * LK + k0 + r) * Hh + h) * Dd + j * 4);
            sVt[j * 4 + 0][r] = vv.x;
            sVt[j * 4 + 1][r] = vv.y;
            sVt[j * 4 + 2][r] = vv.z;
            sVt[j * 4 + 3][r] = vv.w;
        }
        __syncthreads();

        int need = 0;
#pragma unroll
        for (int uu = 0; uu < UW; ++uu) need |= (sP[u0 + uu] >= k0) ? 1 : 0;
        if (need) {
            int k = k0 + lane;
            float4 kr[16];
#pragma unroll
            for (int j = 0; j < 16; ++j)
                kr[j] = *reinterpret_cast<const float4*>(&sK[lane][j * 4]);

#pragma unroll
            for (int uu = 0; uu < UW; ++uu) {
                int p = sP[u0 + uu];
                if (p < k0) continue;
                float s = 0.f;
#pragma unroll
                for (int j = 0; j < 16; ++j)
                    s += dot4(kr[j], *reinterpret_cast<const float4*>(&sQ[u0 + uu][j * 4]));
                float e = (k <= p) ? __expf(s * 0.125f) : 0.f;
                sE[wave][uu][lane] = e;
            }

            float vc[64];                 // lane = d; V column from transposed tile
#pragma unroll
            for (int j = 0; j < 16; ++j) {
                float4 vv = *reinterpret_cast<const float4*>(&sVt[lane][j * 4]);
                vc[4 * j + 0] = vv.x; vc[4 * j + 1] = vv.y;
                vc[4 * j + 2] = vv.z; vc[4 * j + 3] = vv.w;
            }

#pragma unroll
            for (int uu = 0; uu < UW; ++uu) {
                int p = sP[u0 + uu];
                if (p < k0) continue;
                const float4* E4 = reinterpret_cast<const float4*>(sE[wave][uu]);
                float a = acc[uu], L = lsum[uu];
#pragma unroll
                for (int j = 0; j < 16; ++j) {
                    float4 e4 = E4[j];
                    a += e4.x * vc[4 * j + 0] + e4.y * vc[4 * j + 1]
                       + e4.z * vc[4 * j + 2] + e4.w * vc[4 * j + 3];
                    L += (e4.x + e4.y) + (e4.z + e4.w);
                }
                acc[uu] = a; lsum[uu] = L;
            }
        }
        __syncthreads();
    }

#pragma unroll
    for (int uu = 0; uu < UW; ++uu) {
        int u = u0 + uu;
        pacc[(((size_t)bh * NSPL + c) * Uu + u) * Dd + lane] = acc[uu];
        if (lane == 0) pl[((size_t)bh * NSPL + c) * Uu + u] = lsum[uu];
    }
}

// ---------------- Stage 4a: per-chunk V partial sums — (b,c) blocks, float4/(h,d) ---------
__global__ __launch_bounds__(128) void k_part(
    const float* __restrict__ Vp, float* __restrict__ part)
{
    int c = blockIdx.x & (NCH - 1);
    int b = blockIdx.x >> 6;
    int g = threadIdx.x;              // 0..127
    int h = g >> 4, d4 = (g & 15) * 4;

    const float* vb = Vp + ((size_t)(b * LK + c * CHUNK)) * 512 + h * 64 + d4;
    float4 s = make_float4(0.f, 0.f, 0.f, 0.f);
#pragma unroll 4
    for (int l = 0; l < CHUNK; ++l) {
        float4 v = *reinterpret_cast<const float4*>(vb + (size_t)l * 512);
        s.x += v.x; s.y += v.y; s.z += v.z; s.w += v.w;
    }
    int bh = b * 8 + h;
    *reinterpret_cast<float4*>(&part[(size_t)(bh * NCH + c) * Dd + d4]) = s;
}

// ---------------- Stage 4b: in-place exclusive prefix over chunks ----------------
__global__ __launch_bounds__(64) void k_prefix(float* __restrict__ part)
{
    int bh = blockIdx.x;
    int d = threadIdx.x;
    float run = 0.f;
    for (int c = 0; c < NCH; ++c) {
        size_t i = (size_t)(bh * NCH + c) * Dd + d;
        float tmp = part[i];
        part[i] = run;
        run += tmp;
    }
}

// ---------------- Stage 4c: cumsum + inline split-K combine + scatter ----------------
__global__ __launch_bounds__(128) void k_scan(
    const float* __restrict__ Vp, const float* __restrict__ part,
    const int* __restrict__ sel, const float* __restrict__ pacc,
    const float* __restrict__ pl, float* __restrict__ out)
{
    int c = blockIdx.x & (NCH - 1);
    int b = blockIdx.x >> 6;
    int g = threadIdx.x;
    int h = g >> 4, d4 = (g & 15) * 4;
    int bh = b * 8 + h;

    float4 run = *reinterpret_cast<const float4*>(
        &part[(size_t)(bh * NCH + c) * Dd + d4]);

    int l0 = c * CHUNK;
    const float* vb = Vp + ((size_t)(b * LK + l0)) * 512 + h * 64 + d4;
    float* ob = out + ((size_t)(b * LQ + l0)) * 512 + h * 64 + d4;
    const int* sb = sel + bh * LQ + l0;

    for (int l = 0; l < CHUNK; ++l) {
        float4 v = *reinterpret_cast<const float4*>(vb + (size_t)l * 512);
        run.x += v.x; run.y += v.y; run.z += v.z; run.w += v.w;
        int s = sb[l];
        float4 o = run;
        if (s >= 0) {
            float4 A = make_float4(0.f, 0.f, 0.f, 0.f);
            float L = 0.f;
#pragma unroll
            for (int cc = 0; cc < NSPL; ++cc) {
                float4 pa = *reinterpret_cast<const float4*>(
                    &pacc[(((size_t)bh * NSPL + cc) * Uu + s) * Dd + d4]);
                A.x += pa.x; A.y += pa.y; A.z += pa.z; A.w += pa.w;
                L += pl[((size_t)bh * NSPL + cc) * Uu + s];
            }
            float inv = 1.0f / L;
            o = make_float4(A.x * inv, A.y * inv, A.z * inv, A.w * inv);
        }
        *reinterpret_cast<float4*>(ob + (size_t)l * 512) = o;
    }
}

extern "C" void kernel_launch(void* const* d_in, const int* in_sizes, int n_in,
                              void* d_out, int out_size, void* d_ws, size_t ws_size,
                              hipStream_t stream) {
    const float* Qp   = (const float*)d_in[0];
    const float* Kp   = (const float*)d_in[1];
    const float* Vp   = (const float*)d_in[2];
    const int*   idxs = (const int*)d_in[3];
    float* out = (float*)d_out;

    char* w = (char*)d_ws;
    float* M    = (float*)(w);                 // 512K
    int*   sel  = (int*)  (w + 512 * 1024);    // 512K
    int*   Mtop = (int*)  (w + 1024 * 1024);   // 16K
    float* part = (float*)(w + 1040 * 1024);   // 1M (64bh x 64c x 64d)
    float* pacc = (float*)(w + 2064 * 1024);   // 5M (64*8*40*64 f)
    float* pl   = (float*)(w + 7184 * 1024);   // 80K

    k_sampleM<<<Bb * (LQ / 8), 256, 0, stream>>>(Qp, Kp, idxs, M);
    k_topk<<<Bb * Hh, 64, 0, stream>>>(M, Mtop, sel);
    k_attn_part<<<Bb * Hh * NSPL, 256, 0, stream>>>(Qp, Kp, Vp, Mtop, pacc, pl);
    k_part<<<Bb * NCH, 128, 0, stream>>>(Vp, part);
    k_prefix<<<Bb * Hh, 64, 0, stream>>>(part);
    k_scan<<<Bb * NCH, 128, 0, stream>>>(Vp, part, sel, pacc, pl, out);
}

// Round 10
// 202.548 us; speedup vs baseline: 1.0748x; 1.0748x over previous
//
#include <hip/hip_runtime.h>
#include <math.h>

#define Bb 8
#define Hh 8
#define LQ 2048
#define LK 2048
#define Dd 64
#define Uu 40
#define NCH 64
#define CHUNK (LK / NCH)   // 32
#define NSPL 8
#define CK (LK / NSPL)     // 256 keys per split-K chunk
#define UW 10              // queries per wave in k_attn_part
#define SM_BLOCKS (Bb * (LQ / 8))        // 2048 sampleM blocks
#define PART_BLOCKS (Bb * NCH / 2)       // 256 fused k_part blocks (2 chunks each)

typedef float f32x4 __attribute__((ext_vector_type(4)));

__device__ __forceinline__ float dot4(float4 a, float4 b) {
    return a.x * b.x + a.y * b.y + a.z * b.z + a.w * b.w;
}

// ---------------- Stage 1 (fused): sampleM gather + V chunk partial sums ----------------
// sampleM part: at the per-CU L2-gather wall (~84us, r8 analysis). The independent
// V partial-sum stream (HBM-bound) rides along as 256 extra blocks -> overlaps + saves a launch.
__global__ __launch_bounds__(256) void k_sampleM(
    const float* __restrict__ Qp, const float* __restrict__ Kp,
    const int* __restrict__ idxs, const float* __restrict__ Vp,
    float* __restrict__ M, float* __restrict__ part)
{
    int t = threadIdx.x;

    if (blockIdx.x >= SM_BLOCKS) {
        // ---- fused k_part: V per-chunk partial sums (2 chunks per block) ----
        int bid2 = blockIdx.x - SM_BLOCKS;
        int b = bid2 >> 5;                 // 32 blocks per b
        int c = (bid2 & 31) * 2 + (t >> 7);
        int h = (t >> 4) & 7, d4 = (t & 15) * 4;

        const float* vb = Vp + ((size_t)(b * LK + c * CHUNK)) * 512 + h * 64 + d4;
        float4 s = make_float4(0.f, 0.f, 0.f, 0.f);
#pragma unroll 4
        for (int l = 0; l < CHUNK; ++l) {
            float4 v = *reinterpret_cast<const float4*>(vb + (size_t)l * 512);
            s.x += v.x; s.y += v.y; s.z += v.z; s.w += v.w;
        }
        int bh = b * 8 + h;
        *reinterpret_cast<float4*>(&part[(size_t)(bh * NCH + c) * Dd + d4]) = s;
        return;
    }

    int b  = blockIdx.x & 7;      // b-major: round-robin XCD dispatch pins K[b] per XCD L2
    int qt = blockIdx.x >> 3;     // 0..255 (8 queries per block)
    int lane = t & 63, wave = t >> 6;

    __shared__ int sIdx[8 * Uu];
    for (int i = t; i < 8 * Uu; i += 256)
        sIdx[i] = idxs[(qt * 8) * Uu + i];
    __syncthreads();

    const size_t HD = 512;
    const float* Kb = Kp + (size_t)b * LK * HD + lane * 4;

#pragma unroll
    for (int i = 0; i < 2; ++i) {
        int lq = wave * 2 + i;
        int q  = qt * 8 + lq;
        const int* sI = &sIdx[lq * Uu];
#pragma unroll
        for (int ph = 0; ph < 2; ++ph) {
            f32x4 qa = __builtin_nontemporal_load(
                reinterpret_cast<const f32x4*>(
                    Qp + ((size_t)b * LQ + q) * HD + ph * 256) + lane);

            float mx = -INFINITY, sm = 0.f;
#pragma unroll 8
            for (int s = 0; s < Uu; ++s) {
                int kidx = sI[s];
                f32x4 kv = *reinterpret_cast<const f32x4*>(
                    Kb + (size_t)kidx * HD + ph * 256);
                float p = qa[0] * kv[0] + qa[1] * kv[1]
                        + qa[2] * kv[2] + qa[3] * kv[3];
                p += __shfl_xor(p, 1, 64);
                p += __shfl_xor(p, 2, 64);
                p += __shfl_xor(p, 4, 64);
                p += __shfl_xor(p, 8, 64);
                mx = fmaxf(mx, p); sm += p;
            }
            if ((lane & 15) == 0) {
                int h = ph * 4 + (lane >> 4);
                __builtin_nontemporal_store(
                    mx - sm * (1.0f / Uu), &M[((b * 8 + h) << 11) + q]);
            }
        }
    }
}

// ---------------- Stage 2: top-40 per (b,h) — single wave, shuffle argmax ----------------
__global__ __launch_bounds__(64) void k_topk(
    const float* __restrict__ M, int* __restrict__ Mtop, int* __restrict__ sel)
{
    int bh = blockIdx.x;
    int lane = threadIdx.x;
    __shared__ float Ml[LQ];

    for (int j = lane; j < LQ; j += 64) {
        Ml[j] = M[bh * LQ + j];
        sel[bh * LQ + j] = -1;
    }
    __syncthreads();

    float lv = -INFINITY; int li = LQ;
    for (int j = 0; j < 32; ++j) {
        int idx = lane + 64 * j;
        float x = Ml[idx];
        if (x > lv) { lv = x; li = idx; }
    }

    for (int u = 0; u < Uu; ++u) {
        float v = lv; int id = li;
#pragma unroll
        for (int off = 32; off > 0; off >>= 1) {
            float ov = __shfl_xor(v, off, 64);
            int   oi = __shfl_xor(id, off, 64);
            if (ov > v || (ov == v && oi < id)) { v = ov; id = oi; }
        }
        if (lane == 0) {
            Mtop[bh * Uu + u] = id;
            sel[bh * LQ + id] = u;
        }
        if ((id & 63) == lane) {        // owner invalidates + rescans its column
            Ml[id] = -INFINITY;
            lv = -INFINITY; li = LQ;
            for (int j = 0; j < 32; ++j) {
                int idx = lane + 64 * j;
                float x = Ml[idx];
                if (x > lv) { lv = x; li = idx; }
            }
        }
    }
}

// ---------------- Stage 3: split-K partial attention (r3 form: no LDS staging) ----------
__global__ __launch_bounds__(256) void k_attn_part(
    const float* __restrict__ Qp, const float* __restrict__ Kp,
    const float* __restrict__ Vp, const int* __restrict__ Mtop,
    float* __restrict__ pacc, float* __restrict__ pl)
{
    int bh = blockIdx.x >> 3;
    int c  = blockIdx.x & (NSPL - 1);
    int b = bh >> 3, h = bh & 7;
    int lane = threadIdx.x & 63, wave = threadIdx.x >> 6;

    __shared__ float sQ[Uu][Dd];
    __shared__ int   sP[Uu];
    __shared__ float sE[4][UW][Dd];

    if (threadIdx.x < Uu) sP[threadIdx.x] = Mtop[bh * Uu + threadIdx.x];
    __syncthreads();

    int pmax = 0;
#pragma unroll 8
    for (int u = 0; u < Uu; ++u) pmax = max(pmax, sP[u]);

    for (int i = threadIdx.x; i < Uu * Dd; i += 256) {
        int u = i >> 6, d = i & 63;
        sQ[u][d] = Qp[(((size_t)b * LQ + sP[u]) * Hh + h) * Dd + d];
    }
    __syncthreads();

    float acc[UW], lsum[UW];
#pragma unroll
    for (int i = 0; i < UW; ++i) { acc[i] = 0.f; lsum[i] = 0.f; }

    const int u0 = wave * UW;
    for (int t = 0; t < CK / 64; ++t) {
        int k0 = c * CK + t * 64;
        if (pmax < k0) break;             // block-uniform: tiles ascend
        int k  = k0 + lane;

        int need = 0;
#pragma unroll
        for (int uu = 0; uu < UW; ++uu) need |= (sP[u0 + uu] >= k0) ? 1 : 0;
        if (!need) continue;   // wave-uniform skip

        const float4* Kv = reinterpret_cast<const float4*>(
            Kp + (((size_t)b * LK + k) * Hh + h) * Dd);
        float4 kr[16];
#pragma unroll
        for (int j = 0; j < 16; ++j) kr[j] = Kv[j];

#pragma unroll
        for (int uu = 0; uu < UW; ++uu) {
            int p = sP[u0 + uu];
            if (p < k0) continue;
            const float4* Q4 = reinterpret_cast<const float4*>(sQ[u0 + uu]);
            float s = 0.f;
#pragma unroll
            for (int j = 0; j < 16; ++j) s += dot4(kr[j], Q4[j]);
            float e = (k <= p) ? __expf(s * 0.125f) : 0.f;
            sE[wave][uu][lane] = e;
        }

        const float* Vb = Vp + (((size_t)b * LK + k0) * Hh + h) * Dd + lane;
        float vc[64];
#pragma unroll
        for (int kk = 0; kk < 64; ++kk) vc[kk] = Vb[(size_t)kk * (Hh * Dd)];

#pragma unroll
        for (int uu = 0; uu < UW; ++uu) {
            int p = sP[u0 + uu];
            if (p < k0) continue;
            const float4* E4 = reinterpret_cast<const float4*>(sE[wave][uu]);
            float a = acc[uu], L = lsum[uu];
#pragma unroll
            for (int j = 0; j < 16; ++j) {
                float4 e4 = E4[j];
                a += e4.x * vc[4 * j + 0] + e4.y * vc[4 * j + 1]
                   + e4.z * vc[4 * j + 2] + e4.w * vc[4 * j + 3];
                L += (e4.x + e4.y) + (e4.z + e4.w);
            }
            acc[uu] = a; lsum[uu] = L;
        }
    }

#pragma unroll
    for (int uu = 0; uu < UW; ++uu) {
        int u = u0 + uu;
        pacc[(((size_t)bh * NSPL + c) * Uu + u) * Dd + lane] = acc[uu];
        if (lane == 0) pl[((size_t)bh * NSPL + c) * Uu + u] = lsum[uu];
    }
}

// ---------------- Stage 4b: in-place exclusive prefix over chunks ----------------
__global__ __launch_bounds__(64) void k_prefix(float* __restrict__ part)
{
    int bh = blockIdx.x;
    int d = threadIdx.x;
    float run = 0.f;
    for (int c = 0; c < NCH; ++c) {
        size_t i = (size_t)(bh * NCH + c) * Dd + d;
        float tmp = part[i];
        part[i] = run;
        run += tmp;
    }
}

// ---------------- Stage 4c: cumsum + inline split-K combine + scatter ----------------
__global__ __launch_bounds__(128) void k_scan(
    const float* __restrict__ Vp, const float* __restrict__ part,
    const int* __restrict__ sel, const float* __restrict__ pacc,
    const float* __restrict__ pl, float* __restrict__ out)
{
    int c = blockIdx.x & (NCH - 1);
    int b = blockIdx.x >> 6;
    int g = threadIdx.x;
    int h = g >> 4, d4 = (g & 15) * 4;
    int bh = b * 8 + h;

    float4 run = *reinterpret_cast<const float4*>(
        &part[(size_t)(bh * NCH + c) * Dd + d4]);

    int l0 = c * CHUNK;
    const float* vb = Vp + ((size_t)(b * LK + l0)) * 512 + h * 64 + d4;
    float* ob = out + ((size_t)(b * LQ + l0)) * 512 + h * 64 + d4;
    const int* sb = sel + bh * LQ + l0;

    for (int l = 0; l < CHUNK; ++l) {
        float4 v = *reinterpret_cast<const float4*>(vb + (size_t)l * 512);
        run.x += v.x; run.y += v.y; run.z += v.z; run.w += v.w;
        int s = sb[l];
        float4 o = run;
        if (s >= 0) {
            float4 A = make_float4(0.f, 0.f, 0.f, 0.f);
            float L = 0.f;
#pragma unroll
            for (int cc = 0; cc < NSPL; ++cc) {
                float4 pa = *reinterpret_cast<const float4*>(
                    &pacc[(((size_t)bh * NSPL + cc) * Uu + s) * Dd + d4]);
                A.x += pa.x; A.y += pa.y; A.z += pa.z; A.w += pa.w;
                L += pl[((size_t)bh * NSPL + cc) * Uu + s];
            }
            float inv = 1.0f / L;
            o = make_float4(A.x * inv, A.y * inv, A.z * inv, A.w * inv);
        }
        *reinterpret_cast<float4*>(ob + (size_t)l * 512) = o;
    }
}

extern "C" void kernel_launch(void* const* d_in, const int* in_sizes, int n_in,
                              void* d_out, int out_size, void* d_ws, size_t ws_size,
                              hipStream_t stream) {
    const float* Qp   = (const float*)d_in[0];
    const float* Kp   = (const float*)d_in[1];
    const float* Vp   = (const float*)d_in[2];
    const int*   idxs = (const int*)d_in[3];
    float* out = (float*)d_out;

    char* w = (char*)d_ws;
    float* M    = (float*)(w);                 // 512K
    int*   sel  = (int*)  (w + 512 * 1024);    // 512K
    int*   Mtop = (int*)  (w + 1024 * 1024);   // 16K
    float* part = (float*)(w + 1040 * 1024);   // 1M (64bh x 64c x 64d)
    float* pacc = (float*)(w + 2064 * 1024);   // 5M (64*8*40*64 f)
    float* pl   = (float*)(w + 7184 * 1024);   // 80K

    k_sampleM<<<SM_BLOCKS + PART_BLOCKS, 256, 0, stream>>>(Qp, Kp, idxs, Vp, M, part);
    k_topk<<<Bb * Hh, 64, 0, stream>>>(M, Mtop, sel);
    k_attn_part<<<Bb * Hh * NSPL, 256, 0, stream>>>(Qp, Kp, Vp, Mtop, pacc, pl);
    k_prefix<<<Bb * Hh, 64, 0, stream>>>(part);
    k_scan<<<Bb * NCH, 128, 0, stream>>>(Vp, part, sel, pacc, pl, out);
}

// Round 11
// 155.195 us; speedup vs baseline: 1.4027x; 1.3051x over previous
//
#include <hip/hip_runtime.h>
#include <math.h>

#define Bb 8
#define Hh 8
#define LQ 2048
#define LK 2048
#define Dd 64
#define Uu 40
#define NCH 64
#define CHUNK (LK / NCH)   // 32
#define NSPL 8
#define CK (LK / NSPL)     // 256 keys per split-K chunk
#define SM_BLOCKS (Bb * (LQ / 8))        // 2048 sampleM blocks
#define PART_BLOCKS (Bb * NCH / 2)       // 256 fused k_part blocks (2 chunks each)

typedef float f32x4 __attribute__((ext_vector_type(4)));
typedef short bf16x8 __attribute__((ext_vector_type(8)));

__device__ __forceinline__ float dot4(float4 a, float4 b) {
    return a.x * b.x + a.y * b.y + a.z * b.z + a.w * b.w;
}

__device__ __forceinline__ short f2bf(float x) {
    unsigned u = __float_as_uint(x);
    unsigned r = u + 0x7fffu + ((u >> 16) & 1u);   // RNE
    return (short)(r >> 16);
}

__device__ __forceinline__ bf16x8 pack8(float4 a, float4 b) {
    bf16x8 r;
    r[0] = f2bf(a.x); r[1] = f2bf(a.y); r[2] = f2bf(a.z); r[3] = f2bf(a.w);
    r[4] = f2bf(b.x); r[5] = f2bf(b.y); r[6] = f2bf(b.z); r[7] = f2bf(b.w);
    return r;
}

// ---------------- Stage 1 (fused): sampleM gather + V chunk partial sums ----------------
// sampleM: at the per-CU TA-transaction wall (~84us). fp32 kept: selection precision.
__global__ __launch_bounds__(256) void k_sampleM(
    const float* __restrict__ Qp, const float* __restrict__ Kp,
    const int* __restrict__ idxs, const float* __restrict__ Vp,
    float* __restrict__ M, float* __restrict__ part)
{
    int t = threadIdx.x;

    if (blockIdx.x >= SM_BLOCKS) {
        int bid2 = blockIdx.x - SM_BLOCKS;
        int b = bid2 >> 5;
        int c = (bid2 & 31) * 2 + (t >> 7);
        int h = (t >> 4) & 7, d4 = (t & 15) * 4;

        const float* vb = Vp + ((size_t)(b * LK + c * CHUNK)) * 512 + h * 64 + d4;
        float4 s = make_float4(0.f, 0.f, 0.f, 0.f);
#pragma unroll 4
        for (int l = 0; l < CHUNK; ++l) {
            float4 v = *reinterpret_cast<const float4*>(vb + (size_t)l * 512);
            s.x += v.x; s.y += v.y; s.z += v.z; s.w += v.w;
        }
        int bh = b * 8 + h;
        *reinterpret_cast<float4*>(&part[(size_t)(bh * NCH + c) * Dd + d4]) = s;
        return;
    }

    int b  = blockIdx.x & 7;
    int qt = blockIdx.x >> 3;
    int lane = t & 63, wave = t >> 6;

    __shared__ int sIdx[8 * Uu];
    for (int i = t; i < 8 * Uu; i += 256)
        sIdx[i] = idxs[(qt * 8) * Uu + i];
    __syncthreads();

    const size_t HD = 512;
    const float* Kb = Kp + (size_t)b * LK * HD + lane * 4;

#pragma unroll
    for (int i = 0; i < 2; ++i) {
        int lq = wave * 2 + i;
        int q  = qt * 8 + lq;
        const int* sI = &sIdx[lq * Uu];
#pragma unroll
        for (int ph = 0; ph < 2; ++ph) {
            f32x4 qa = __builtin_nontemporal_load(
                reinterpret_cast<const f32x4*>(
                    Qp + ((size_t)b * LQ + q) * HD + ph * 256) + lane);

            float mx = -INFINITY, sm = 0.f;
#pragma unroll 8
            for (int s = 0; s < Uu; ++s) {
                int kidx = sI[s];
                f32x4 kv = *reinterpret_cast<const f32x4*>(
                    Kb + (size_t)kidx * HD + ph * 256);
                float p = qa[0] * kv[0] + qa[1] * kv[1]
                        + qa[2] * kv[2] + qa[3] * kv[3];
                p += __shfl_xor(p, 1, 64);
                p += __shfl_xor(p, 2, 64);
                p += __shfl_xor(p, 4, 64);
                p += __shfl_xor(p, 8, 64);
                mx = fmaxf(mx, p); sm += p;
            }
            if ((lane & 15) == 0) {
                int h = ph * 4 + (lane >> 4);
                __builtin_nontemporal_store(
                    mx - sm * (1.0f / Uu), &M[((b * 8 + h) << 11) + q]);
            }
        }
    }
}

// ---------------- Stage 2: top-40 per (b,h) — single wave, shuffle argmax ----------------
__global__ __launch_bounds__(64) void k_topk(
    const float* __restrict__ M, int* __restrict__ Mtop, int* __restrict__ sel)
{
    int bh = blockIdx.x;
    int lane = threadIdx.x;
    __shared__ float Ml[LQ];

    for (int j = lane; j < LQ; j += 64) {
        Ml[j] = M[bh * LQ + j];
        sel[bh * LQ + j] = -1;
    }
    __syncthreads();

    float lv = -INFINITY; int li = LQ;
    for (int j = 0; j < 32; ++j) {
        int idx = lane + 64 * j;
        float x = Ml[idx];
        if (x > lv) { lv = x; li = idx; }
    }

    for (int u = 0; u < Uu; ++u) {
        float v = lv; int id = li;
#pragma unroll
        for (int off = 32; off > 0; off >>= 1) {
            float ov = __shfl_xor(v, off, 64);
            int   oi = __shfl_xor(id, off, 64);
            if (ov > v || (ov == v && oi < id)) { v = ov; id = oi; }
        }
        if (lane == 0) {
            Mtop[bh * Uu + u] = id;
            sel[bh * LQ + id] = u;
        }
        if ((id & 63) == lane) {
            Ml[id] = -INFINITY;
            lv = -INFINITY; li = LQ;
            for (int j = 0; j < 32; ++j) {
                int idx = lane + 64 * j;
                float x = Ml[idx];
                if (x > lv) { lv = x; li = idx; }
            }
        }
    }
}

// ---------------- Stage 3: split-K partial attention via bf16 MFMA ----------------
// Per block (bh, c): 4 key-tiles of 64. QK^T: wave w owns keys [16w,16w+16);
// S tile D-layout: key=(lane>>4)*4+reg, q=lane&15 (m89). P->LDS bf16 [48][80].
// PV: wave w owns d-block [16w,16w+16); A=P from LDS, B=V from global scalars.
__global__ __launch_bounds__(256) void k_attn_part(
    const float* __restrict__ Qp, const float* __restrict__ Kp,
    const float* __restrict__ Vp, const int* __restrict__ Mtop,
    float* __restrict__ pacc, float* __restrict__ pl)
{
    int bh = blockIdx.x >> 3;
    int c  = blockIdx.x & (NSPL - 1);
    int b = bh >> 3, h = bh & 7;
    int t = threadIdx.x;
    int lane = t & 63, w = t >> 6;
    int col = lane & 15, hi = lane >> 4;

    __shared__ int sP[48];
    __shared__ __align__(16) short sPl[48][80];   // P tile bf16, 160B rows (16B-mult)
    __shared__ float sL[4][48];

    if (t < 48) sP[t] = (t < Uu) ? Mtop[bh * Uu + t] : -1;
    __syncthreads();

    int pmax = 0;
#pragma unroll 8
    for (int u = 0; u < Uu; ++u) pmax = max(pmax, sP[u]);

    // Q B-fragments in registers: lane: q = qb*16+col, d = ks*32 + hi*8 + e
    bf16x8 qf[3][2];
#pragma unroll
    for (int qb = 0; qb < 3; ++qb) {
        int q = qb * 16 + col;
        int row = sP[q];
#pragma unroll
        for (int ks = 0; ks < 2; ++ks) {
            const float* qp = Qp + (((size_t)b * LQ + max(row, 0)) * Hh + h) * Dd
                              + ks * 32 + hi * 8;
            float4 x = *reinterpret_cast<const float4*>(qp);
            float4 y = *reinterpret_cast<const float4*>(qp + 4);
            bf16x8 f = pack8(x, y);
            if (row < 0) f = (bf16x8)(short)0;
            qf[qb][ks] = f;
        }
    }

    f32x4 oacc[3];
    float lsum[3];
#pragma unroll
    for (int qb = 0; qb < 3; ++qb) { oacc[qb] = (f32x4)0.f; lsum[qb] = 0.f; }

    for (int tt = 0; tt < CK / 64; ++tt) {
        int k0 = c * CK + tt * 64;
        if (pmax < k0) break;

        // ---- QK^T: A = K rows [16w..16w+16), lane: key=k0+16w+col, d=ks*32+hi*8+e
        bf16x8 af[2];
#pragma unroll
        for (int ks = 0; ks < 2; ++ks) {
            const float* kp = Kp + (((size_t)b * LK + k0 + 16 * w + col) * Hh + h) * Dd
                              + ks * 32 + hi * 8;
            float4 x = *reinterpret_cast<const float4*>(kp);
            float4 y = *reinterpret_cast<const float4*>(kp + 4);
            af[ks] = pack8(x, y);
        }

#pragma unroll
        for (int qb = 0; qb < 3; ++qb) {
            f32x4 s = (f32x4)0.f;
            s = __builtin_amdgcn_mfma_f32_16x16x32_bf16(af[0], qf[qb][0], s, 0, 0, 0);
            s = __builtin_amdgcn_mfma_f32_16x16x32_bf16(af[1], qf[qb][1], s, 0, 0, 0);

            int p = sP[qb * 16 + col];
            int kbase = k0 + 16 * w + hi * 4;
            float e0 = (kbase + 0 <= p) ? __expf(s[0] * 0.125f) : 0.f;
            float e1 = (kbase + 1 <= p) ? __expf(s[1] * 0.125f) : 0.f;
            float e2 = (kbase + 2 <= p) ? __expf(s[2] * 0.125f) : 0.f;
            float e3 = (kbase + 3 <= p) ? __expf(s[3] * 0.125f) : 0.f;
            lsum[qb] += (e0 + e1) + (e2 + e3);

            int q = qb * 16 + col;
            int kl = 16 * w + hi * 4;
            unsigned p01 = (unsigned)(unsigned short)f2bf(e0)
                         | ((unsigned)(unsigned short)f2bf(e1) << 16);
            unsigned p23 = (unsigned)(unsigned short)f2bf(e2)
                         | ((unsigned)(unsigned short)f2bf(e3) << 16);
            *reinterpret_cast<unsigned*>(&sPl[q][kl])     = p01;
            *reinterpret_cast<unsigned*>(&sPl[q][kl + 2]) = p23;
        }
        __syncthreads();

        // ---- PV: wave w owns d-block; B = V[k=ks*32+hi*8+e][d=16w+col]
#pragma unroll
        for (int ks = 0; ks < 2; ++ks) {
            const float* vb = Vp + (((size_t)b * LK + k0 + ks * 32 + hi * 8) * Hh + h) * Dd
                              + 16 * w + col;
            float4 x, y;
            x.x = vb[0];       x.y = vb[512];      x.z = vb[1024];     x.w = vb[1536];
            y.x = vb[2048];    y.y = vb[2560];     y.z = vb[3072];     y.w = vb[3584];
            bf16x8 vf = pack8(x, y);
#pragma unroll
            for (int qb = 0; qb < 3; ++qb) {
                bf16x8 pf = *reinterpret_cast<const bf16x8*>(&sPl[qb * 16 + col][ks * 32 + hi * 8]);
                oacc[qb] = __builtin_amdgcn_mfma_f32_16x16x32_bf16(pf, vf, oacc[qb], 0, 0, 0);
            }
        }
        __syncthreads();
    }

    // ---- epilogue: O writes (D-layout: q = qb*16+hi*4+reg, d = 16w+col)
#pragma unroll
    for (int qb = 0; qb < 3; ++qb) {
#pragma unroll
        for (int r = 0; r < 4; ++r) {
            int q = qb * 16 + hi * 4 + r;
            if (q < Uu)
                pacc[(((size_t)bh * NSPL + c) * Uu + q) * Dd + 16 * w + col] = oacc[qb][r];
        }
        lsum[qb] += __shfl_xor(lsum[qb], 16, 64);
        lsum[qb] += __shfl_xor(lsum[qb], 32, 64);
        if (lane < 16) sL[w][qb * 16 + lane] = lsum[qb];
    }
    __syncthreads();
    if (t < Uu)
        pl[((size_t)bh * NSPL + c) * Uu + t] =
            sL[0][t] + sL[1][t] + sL[2][t] + sL[3][t];
}

// ---------------- Stage 4b: in-place exclusive prefix over chunks ----------------
__global__ __launch_bounds__(64) void k_prefix(float* __restrict__ part)
{
    int bh = blockIdx.x;
    int d = threadIdx.x;
    float run = 0.f;
    for (int c = 0; c < NCH; ++c) {
        size_t i = (size_t)(bh * NCH + c) * Dd + d;
        float tmp = part[i];
        part[i] = run;
        run += tmp;
    }
}

// ---------------- Stage 4c: cumsum + inline split-K combine + scatter ----------------
__global__ __launch_bounds__(128) void k_scan(
    const float* __restrict__ Vp, const float* __restrict__ part,
    const int* __restrict__ sel, const float* __restrict__ pacc,
    const float* __restrict__ pl, float* __restrict__ out)
{
    int c = blockIdx.x & (NCH - 1);
    int b = blockIdx.x >> 6;
    int g = threadIdx.x;
    int h = g >> 4, d4 = (g & 15) * 4;
    int bh = b * 8 + h;

    float4 run = *reinterpret_cast<const float4*>(
        &part[(size_t)(bh * NCH + c) * Dd + d4]);

    int l0 = c * CHUNK;
    const float* vb = Vp + ((size_t)(b * LK + l0)) * 512 + h * 64 + d4;
    float* ob = out + ((size_t)(b * LQ + l0)) * 512 + h * 64 + d4;
    const int* sb = sel + bh * LQ + l0;

    for (int l = 0; l < CHUNK; ++l) {
        float4 v = *reinterpret_cast<const float4*>(vb + (size_t)l * 512);
        run.x += v.x; run.y += v.y; run.z += v.z; run.w += v.w;
        int s = sb[l];
        float4 o = run;
        if (s >= 0) {
            float4 A = make_float4(0.f, 0.f, 0.f, 0.f);
            float L = 0.f;
#pragma unroll
            for (int cc = 0; cc < NSPL; ++cc) {
                float4 pa = *reinterpret_cast<const float4*>(
                    &pacc[(((size_t)bh * NSPL + cc) * Uu + s) * Dd + d4]);
                A.x += pa.x; A.y += pa.y; A.z += pa.z; A.w += pa.w;
                L += pl[((size_t)bh * NSPL + cc) * Uu + s];
            }
            float inv = 1.0f / L;
            o = make_float4(A.x * inv, A.y * inv, A.z * inv, A.w * inv);
        }
        *reinterpret_cast<float4*>(ob + (size_t)l * 512) = o;
    }
}

extern "C" void kernel_launch(void* const* d_in, const int* in_sizes, int n_in,
                              void* d_out, int out_size, void* d_ws, size_t ws_size,
                              hipStream_t stream) {
    const float* Qp   = (const float*)d_in[0];
    const float* Kp   = (const float*)d_in[1];
    const float* Vp   = (const float*)d_in[2];
    const int*   idxs = (const int*)d_in[3];
    float* out = (float*)d_out;

    char* w = (char*)d_ws;
    float* M    = (float*)(w);                 // 512K
    int*   sel  = (int*)  (w + 512 * 1024);    // 512K
    int*   Mtop = (int*)  (w + 1024 * 1024);   // 16K
    float* part = (float*)(w + 1040 * 1024);   // 1M
    float* pacc = (float*)(w + 2064 * 1024);   // 5M
    float* pl   = (float*)(w + 7184 * 1024);   // 80K

    k_sampleM<<<SM_BLOCKS + PART_BLOCKS, 256, 0, stream>>>(Qp, Kp, idxs, Vp, M, part);
    k_topk<<<Bb * Hh, 64, 0, stream>>>(M, Mtop, sel);
    k_attn_part<<<Bb * Hh * NSPL, 256, 0, stream>>>(Qp, Kp, Vp, Mtop, pacc, pl);
    k_prefix<<<Bb * Hh, 64, 0, stream>>>(part);
    k_scan<<<Bb * NCH, 128, 0, stream>>>(Vp, part, sel, pacc, pl, out);
}

// Round 12
// 151.357 us; speedup vs baseline: 1.4383x; 1.0254x over previous
//
#include <hip/hip_runtime.h>
#include <math.h>

#define Bb 8
#define Hh 8
#define LQ 2048
#define LK 2048
#define Dd 64
#define Uu 40
#define NCH 64
#define CHUNK (LK / NCH)   // 32
#define NSPL 8
#define CK (LK / NSPL)     // 256 keys per split-K chunk
#define SM_BLOCKS (Bb * (LQ / 8))        // 2048 sampleM blocks
#define PART_BLOCKS (Bb * NCH / 2)       // 256 fused k_part blocks (2 chunks each)

typedef float f32x4 __attribute__((ext_vector_type(4)));
typedef short bf16x8 __attribute__((ext_vector_type(8)));

__device__ __forceinline__ float dot4(float4 a, float4 b) {
    return a.x * b.x + a.y * b.y + a.z * b.z + a.w * b.w;
}

__device__ __forceinline__ short f2bf(float x) {
    unsigned u = __float_as_uint(x);
    unsigned r = u + 0x7fffu + ((u >> 16) & 1u);   // RNE
    return (short)(r >> 16);
}

__device__ __forceinline__ bf16x8 pack8(float4 a, float4 b) {
    bf16x8 r;
    r[0] = f2bf(a.x); r[1] = f2bf(a.y); r[2] = f2bf(a.z); r[3] = f2bf(a.w);
    r[4] = f2bf(b.x); r[5] = f2bf(b.y); r[6] = f2bf(b.z); r[7] = f2bf(b.w);
    return r;
}

// ---------------- Stage 1 (fused): sampleM gather + V chunk partial sums ----------------
// sampleM: at the per-CU gather-transaction wall (~86us). fp32 kept: selection precision.
__global__ __launch_bounds__(256) void k_sampleM(
    const float* __restrict__ Qp, const float* __restrict__ Kp,
    const int* __restrict__ idxs, const float* __restrict__ Vp,
    float* __restrict__ M, float* __restrict__ part)
{
    int t = threadIdx.x;

    if (blockIdx.x >= SM_BLOCKS) {
        int bid2 = blockIdx.x - SM_BLOCKS;
        int b = bid2 >> 5;
        int c = (bid2 & 31) * 2 + (t >> 7);
        int h = (t >> 4) & 7, d4 = (t & 15) * 4;

        const float* vb = Vp + ((size_t)(b * LK + c * CHUNK)) * 512 + h * 64 + d4;
        float4 s = make_float4(0.f, 0.f, 0.f, 0.f);
#pragma unroll 4
        for (int l = 0; l < CHUNK; ++l) {
            float4 v = *reinterpret_cast<const float4*>(vb + (size_t)l * 512);
            s.x += v.x; s.y += v.y; s.z += v.z; s.w += v.w;
        }
        int bh = b * 8 + h;
        *reinterpret_cast<float4*>(&part[(size_t)(bh * NCH + c) * Dd + d4]) = s;
        return;
    }

    int b  = blockIdx.x & 7;
    int qt = blockIdx.x >> 3;
    int lane = t & 63, wave = t >> 6;

    __shared__ int sIdx[8 * Uu];
    for (int i = t; i < 8 * Uu; i += 256)
        sIdx[i] = idxs[(qt * 8) * Uu + i];
    __syncthreads();

    const size_t HD = 512;
    const float* Kb = Kp + (size_t)b * LK * HD + lane * 4;

#pragma unroll
    for (int i = 0; i < 2; ++i) {
        int lq = wave * 2 + i;
        int q  = qt * 8 + lq;
        const int* sI = &sIdx[lq * Uu];
#pragma unroll
        for (int ph = 0; ph < 2; ++ph) {
            f32x4 qa = __builtin_nontemporal_load(
                reinterpret_cast<const f32x4*>(
                    Qp + ((size_t)b * LQ + q) * HD + ph * 256) + lane);

            float mx = -INFINITY, sm = 0.f;
#pragma unroll 8
            for (int s = 0; s < Uu; ++s) {
                int kidx = sI[s];
                f32x4 kv = *reinterpret_cast<const f32x4*>(
                    Kb + (size_t)kidx * HD + ph * 256);
                float p = qa[0] * kv[0] + qa[1] * kv[1]
                        + qa[2] * kv[2] + qa[3] * kv[3];
                p += __shfl_xor(p, 1, 64);
                p += __shfl_xor(p, 2, 64);
                p += __shfl_xor(p, 4, 64);
                p += __shfl_xor(p, 8, 64);
                mx = fmaxf(mx, p); sm += p;
            }
            if ((lane & 15) == 0) {
                int h = ph * 4 + (lane >> 4);
                __builtin_nontemporal_store(
                    mx - sm * (1.0f / Uu), &M[((b * 8 + h) << 11) + q]);
            }
        }
    }
}

// ---------------- Stage 2 (fused): topk (blocks 0..63) + part-prefix (blocks 64..127) ----
__global__ __launch_bounds__(64) void k_topk_prefix(
    const float* __restrict__ M, int* __restrict__ Mtop, int* __restrict__ sel,
    float* __restrict__ part)
{
    if (blockIdx.x >= Bb * Hh) {
        // in-place exclusive prefix over V chunk sums
        int bh = blockIdx.x - Bb * Hh;
        int d = threadIdx.x;
        float run = 0.f;
        for (int c = 0; c < NCH; ++c) {
            size_t i = (size_t)(bh * NCH + c) * Dd + d;
            float tmp = part[i];
            part[i] = run;
            run += tmp;
        }
        return;
    }

    int bh = blockIdx.x;
    int lane = threadIdx.x;
    __shared__ float Ml[LQ];

    for (int j = lane; j < LQ; j += 64) {
        Ml[j] = M[bh * LQ + j];
        sel[bh * LQ + j] = -1;
    }
    __syncthreads();

    float lv = -INFINITY; int li = LQ;
    for (int j = 0; j < 32; ++j) {
        int idx = lane + 64 * j;
        float x = Ml[idx];
        if (x > lv) { lv = x; li = idx; }
    }

    for (int u = 0; u < Uu; ++u) {
        float v = lv; int id = li;
#pragma unroll
        for (int off = 32; off > 0; off >>= 1) {
            float ov = __shfl_xor(v, off, 64);
            int   oi = __shfl_xor(id, off, 64);
            if (ov > v || (ov == v && oi < id)) { v = ov; id = oi; }
        }
        if (lane == 0) {
            Mtop[bh * Uu + u] = id;
            sel[bh * LQ + id] = u;
        }
        if ((id & 63) == lane) {
            Ml[id] = -INFINITY;
            lv = -INFINITY; li = LQ;
            for (int j = 0; j < 32; ++j) {
                int idx = lane + 64 * j;
                float x = Ml[idx];
                if (x > lv) { lv = x; li = idx; }
            }
        }
    }
}

// ---------------- Stage 3: split-K partial attention via bf16 MFMA ----------------
// Double-buffered P tile -> ONE barrier per key-tile.
__global__ __launch_bounds__(256) void k_attn_part(
    const float* __restrict__ Qp, const float* __restrict__ Kp,
    const float* __restrict__ Vp, const int* __restrict__ Mtop,
    float* __restrict__ pacc, float* __restrict__ pl)
{
    int bh = blockIdx.x >> 3;
    int c  = blockIdx.x & (NSPL - 1);
    int b = bh >> 3, h = bh & 7;
    int t = threadIdx.x;
    int lane = t & 63, w = t >> 6;
    int col = lane & 15, hi = lane >> 4;

    __shared__ int sP[48];
    __shared__ __align__(16) short sPl[2][48][80];   // double-buffered P tile (bf16)
    __shared__ float sL[4][48];

    if (t < 48) sP[t] = (t < Uu) ? Mtop[bh * Uu + t] : -1;
    __syncthreads();

    int pmax = 0;
#pragma unroll 8
    for (int u = 0; u < Uu; ++u) pmax = max(pmax, sP[u]);

    // Q B-fragments: lane: q = qb*16+col, d = ks*32 + hi*8 + e
    bf16x8 qf[3][2];
#pragma unroll
    for (int qb = 0; qb < 3; ++qb) {
        int q = qb * 16 + col;
        int row = sP[q];
#pragma unroll
        for (int ks = 0; ks < 2; ++ks) {
            const float* qp = Qp + (((size_t)b * LQ + max(row, 0)) * Hh + h) * Dd
                              + ks * 32 + hi * 8;
            float4 x = *reinterpret_cast<const float4*>(qp);
            float4 y = *reinterpret_cast<const float4*>(qp + 4);
            bf16x8 f = pack8(x, y);
            if (row < 0) f = (bf16x8)(short)0;
            qf[qb][ks] = f;
        }
    }

    f32x4 oacc[3];
    float lsum[3];
#pragma unroll
    for (int qb = 0; qb < 3; ++qb) { oacc[qb] = (f32x4)0.f; lsum[qb] = 0.f; }

    for (int tt = 0; tt < CK / 64; ++tt) {
        int k0 = c * CK + tt * 64;
        if (pmax < k0) break;
        int pb = tt & 1;

        // ---- QK^T: A = K rows [16w..16w+16)
        bf16x8 af[2];
#pragma unroll
        for (int ks = 0; ks < 2; ++ks) {
            const float* kp = Kp + (((size_t)b * LK + k0 + 16 * w + col) * Hh + h) * Dd
                              + ks * 32 + hi * 8;
            float4 x = *reinterpret_cast<const float4*>(kp);
            float4 y = *reinterpret_cast<const float4*>(kp + 4);
            af[ks] = pack8(x, y);
        }

#pragma unroll
        for (int qb = 0; qb < 3; ++qb) {
            f32x4 s = (f32x4)0.f;
            s = __builtin_amdgcn_mfma_f32_16x16x32_bf16(af[0], qf[qb][0], s, 0, 0, 0);
            s = __builtin_amdgcn_mfma_f32_16x16x32_bf16(af[1], qf[qb][1], s, 0, 0, 0);

            int p = sP[qb * 16 + col];
            int kbase = k0 + 16 * w + hi * 4;
            float e0 = (kbase + 0 <= p) ? __expf(s[0] * 0.125f) : 0.f;
            float e1 = (kbase + 1 <= p) ? __expf(s[1] * 0.125f) : 0.f;
            float e2 = (kbase + 2 <= p) ? __expf(s[2] * 0.125f) : 0.f;
            float e3 = (kbase + 3 <= p) ? __expf(s[3] * 0.125f) : 0.f;
            lsum[qb] += (e0 + e1) + (e2 + e3);

            int q = qb * 16 + col;
            int kl = 16 * w + hi * 4;
            unsigned p01 = (unsigned)(unsigned short)f2bf(e0)
                         | ((unsigned)(unsigned short)f2bf(e1) << 16);
            unsigned p23 = (unsigned)(unsigned short)f2bf(e2)
                         | ((unsigned)(unsigned short)f2bf(e3) << 16);
            *reinterpret_cast<unsigned*>(&sPl[pb][q][kl])     = p01;
            *reinterpret_cast<unsigned*>(&sPl[pb][q][kl + 2]) = p23;
        }
        __syncthreads();     // single barrier: P[pb] written; next iter writes pb^1

        // ---- PV: wave w owns d-block; B = V[k][d=16w+col]
#pragma unroll
        for (int ks = 0; ks < 2; ++ks) {
            const float* vb = Vp + (((size_t)b * LK + k0 + ks * 32 + hi * 8) * Hh + h) * Dd
                              + 16 * w + col;
            float4 x, y;
            x.x = vb[0];       x.y = vb[512];      x.z = vb[1024];     x.w = vb[1536];
            y.x = vb[2048];    y.y = vb[2560];     y.z = vb[3072];     y.w = vb[3584];
            bf16x8 vf = pack8(x, y);
#pragma unroll
            for (int qb = 0; qb < 3; ++qb) {
                bf16x8 pf = *reinterpret_cast<const bf16x8*>(
                    &sPl[pb][qb * 16 + col][ks * 32 + hi * 8]);
                oacc[qb] = __builtin_amdgcn_mfma_f32_16x16x32_bf16(pf, vf, oacc[qb], 0, 0, 0);
            }
        }
    }

    // ---- epilogue
#pragma unroll
    for (int qb = 0; qb < 3; ++qb) {
#pragma unroll
        for (int r = 0; r < 4; ++r) {
            int q = qb * 16 + hi * 4 + r;
            if (q < Uu)
                pacc[(((size_t)bh * NSPL + c) * Uu + q) * Dd + 16 * w + col] = oacc[qb][r];
        }
        lsum[qb] += __shfl_xor(lsum[qb], 16, 64);
        lsum[qb] += __shfl_xor(lsum[qb], 32, 64);
        if (lane < 16) sL[w][qb * 16 + lane] = lsum[qb];
    }
    __syncthreads();
    if (t < Uu)
        pl[((size_t)bh * NSPL + c) * Uu + t] =
            sL[0][t] + sL[1][t] + sL[2][t] + sL[3][t];
}

// ---------------- Stage 4: cumsum + inline split-K combine + scatter ----------------
__global__ __launch_bounds__(128) void k_scan(
    const float* __restrict__ Vp, const float* __restrict__ part,
    const int* __restrict__ sel, const float* __restrict__ pacc,
    const float* __restrict__ pl, float* __restrict__ out)
{
    int c = blockIdx.x & (NCH - 1);
    int b = blockIdx.x >> 6;
    int g = threadIdx.x;
    int h = g >> 4, d4 = (g & 15) * 4;
    int bh = b * 8 + h;

    float4 run = *reinterpret_cast<const float4*>(
        &part[(size_t)(bh * NCH + c) * Dd + d4]);

    int l0 = c * CHUNK;
    const float* vb = Vp + ((size_t)(b * LK + l0)) * 512 + h * 64 + d4;
    float* ob = out + ((size_t)(b * LQ + l0)) * 512 + h * 64 + d4;
    const int* sb = sel + bh * LQ + l0;

#pragma unroll 4
    for (int l = 0; l < CHUNK; ++l) {
        float4 v = *reinterpret_cast<const float4*>(vb + (size_t)l * 512);
        run.x += v.x; run.y += v.y; run.z += v.z; run.w += v.w;
        int s = sb[l];
        float4 o = run;
        if (s >= 0) {
            float4 A = make_float4(0.f, 0.f, 0.f, 0.f);
            float L = 0.f;
#pragma unroll
            for (int cc = 0; cc < NSPL; ++cc) {
                float4 pa = *reinterpret_cast<const float4*>(
                    &pacc[(((size_t)bh * NSPL + cc) * Uu + s) * Dd + d4]);
                A.x += pa.x; A.y += pa.y; A.z += pa.z; A.w += pa.w;
                L += pl[((size_t)bh * NSPL + cc) * Uu + s];
            }
            float inv = 1.0f / L;
            o = make_float4(A.x * inv, A.y * inv, A.z * inv, A.w * inv);
        }
        *reinterpret_cast<float4*>(ob + (size_t)l * 512) = o;
    }
}

extern "C" void kernel_launch(void* const* d_in, const int* in_sizes, int n_in,
                              void* d_out, int out_size, void* d_ws, size_t ws_size,
                              hipStream_t stream) {
    const float* Qp   = (const float*)d_in[0];
    const float* Kp   = (const float*)d_in[1];
    const float* Vp   = (const float*)d_in[2];
    const int*   idxs = (const int*)d_in[3];
    float* out = (float*)d_out;

    char* w = (char*)d_ws;
    float* M    = (float*)(w);                 // 512K
    int*   sel  = (int*)  (w + 512 * 1024);    // 512K
    int*   Mtop = (int*)  (w + 1024 * 1024);   // 16K
    float* part = (float*)(w + 1040 * 1024);   // 1M
    float* pacc = (float*)(w + 2064 * 1024);   // 5M
    float* pl   = (float*)(w + 7184 * 1024);   // 80K

    k_sampleM<<<SM_BLOCKS + PART_BLOCKS, 256, 0, stream>>>(Qp, Kp, idxs, Vp, M, part);
    k_topk_prefix<<<2 * Bb * Hh, 64, 0, stream>>>(M, Mtop, sel, part);
    k_attn_part<<<Bb * Hh * NSPL, 256, 0, stream>>>(Qp, Kp, Vp, Mtop, pacc, pl);
    k_scan<<<Bb * NCH, 128, 0, stream>>>(Vp, part, sel, pacc, pl, out);
}